// Round 4
// baseline (391.651 us; speedup 1.0000x reference)
//
#include <hip/hip_runtime.h>
#include <math.h>

#define Bn   128
#define Sn   512
#define HIDn 768
#define OUTn 200
#define MSEG 16
#define NPAD 224   // OUT padded to 14 MFMA n-tiles of 16
#define NT   14
#define NTW  7     // n-tiles per wave (N split across the 2 waves: nh=0/1)
#define ROWS 32    // rows per block (1 segment); block = 128 thr = 2 waves

typedef __attribute__((ext_vector_type(8))) short short8;
typedef __attribute__((ext_vector_type(4))) float f32x4;

// fp32 -> bf16 round-to-nearest-even (finite inputs)
static __device__ inline unsigned short f2bf(float f) {
  union { float f; unsigned u; } v; v.f = f;
  unsigned r = v.u + 0x7FFFu + ((v.u >> 16) & 1u);
  return (unsigned short)(r >> 16);
}

// saturating fast tanh: e = exp(-2|x|) in (0,1], never overflows
static __device__ inline float fast_tanh(float x) {
  float t = fabsf(x);
  float e = __expf(-2.f * t);
  float r = (1.f - e) * __builtin_amdgcn_rcpf(1.f + e);
  return copysignf(r, x);
}

// one-time: WhF = bf16(Wh^T) in MFMA B-fragment order:
// elem (n,k) -> ((k>>5)*NT + (n>>4))*512 + ((k>>3)&3)*128 + (n&15)*8 + (k&7)
// Cols 200..223 zero-padded.  vP = v zero-padded to NPAD.
__global__ __launch_bounds__(256) void setup_kernel(
    const float* __restrict__ Wh, const float* __restrict__ v,
    unsigned short* __restrict__ WhF, float* __restrict__ vP) {
  int idx = blockIdx.x * 256 + threadIdx.x;   // grid 672 -> 172032 = NPAD*HIDn
  if (blockIdx.x == 0 && threadIdx.x < NPAD)
    vP[threadIdx.x] = (threadIdx.x < OUTn) ? v[threadIdx.x] : 0.f;
  if (idx < NPAD * HIDn) {
    int n = idx / HIDn;
    int k = idx - n * HIDn;
    float val = (n < OUTn) ? Wh[(size_t)k * OUTn + n] : 0.f;
    size_t d = ((size_t)(k >> 5) * NT + (n >> 4)) * 512
             + ((k >> 3) & 3) * 128 + (n & 15) * 8 + (k & 7);
    WhF[d] = f2bf(val);
  }
}

// biasP[b][n] = b[n] + u[b]@Wu[:,n] + p[b]@Wp[:,n], zero-padded to NPAD
__global__ __launch_bounds__(256) void bias_kernel(
    const float* __restrict__ u, const float* __restrict__ p,
    const float* __restrict__ Wu, const float* __restrict__ Wp,
    const float* __restrict__ bvec, float* __restrict__ biasP) {
  int b = blockIdx.x;
  __shared__ float ul[OUTn], pl[OUTn];
  int tid = threadIdx.x;
  if (tid < OUTn) { ul[tid] = u[b * OUTn + tid]; pl[tid] = p[b * OUTn + tid]; }
  __syncthreads();
  if (tid < NPAD) {
    float s0 = 0.f, s1 = 0.f;
    if (tid < OUTn) {
      s0 = bvec[tid];
      for (int k = 0; k < OUTn; k += 2) {
        s0 += ul[k] * Wu[k * OUTn + tid] + pl[k] * Wp[k * OUTn + tid];
        s1 += ul[k + 1] * Wu[(k + 1) * OUTn + tid] + pl[k + 1] * Wp[(k + 1) * OUTn + tid];
      }
    }
    biasP[(size_t)b * NPAD + tid] = s0 + s1;
  }
}

// Fused: block = 128 thr = 2 waves = 32 rows (1 segment).  A reg-staged
// (global float4 -> bf16 -> LDS) in 2 K-halves; stage reads are LINEAR over
// the 48KB half-panel so each wave instruction covers 1-2KB contiguous HBM.
// Wave nh owns 7 n-tiles x all 32 rows (acc 2x7).  LDS chunk XOR-swizzle
// (crb ^ row&7) -> conflict-free ds_read_b128 A-frags, zero f2bf in K-loop.
// 31KB LDS -> ~5 blocks/CU, all independently staggered (no lockstep drains).
__global__ __launch_bounds__(128) void fused_kernel(
    const float* __restrict__ H, const unsigned short* __restrict__ WhF,
    const float* __restrict__ biasP, const float* __restrict__ vP,
    const int* __restrict__ offs, float* __restrict__ out) {
  __shared__ unsigned short __attribute__((aligned(16))) Abf[ROWS * 384]; // 24KB, one K-half, swizzled
  __shared__ float scp[2][ROWS];       // partial scores per n-half
  __shared__ float o_l[2][HIDn];       // per-wave weighted-sum partials

  int tid = threadIdx.x, wave = tid >> 6, lane = tid & 63;
  int quad = lane >> 4, l16 = lane & 15;
  int nh = wave;
  int bid = blockIdx.x;
  int b = bid >> 4;              // 16 blocks (segments) per batch
  int seg = bid & 15;
  int s0 = seg << 5;

  const float* Hblk = H + (size_t)(b * Sn + s0) * HIDn;

  f32x4 acc[2][NTW];
#pragma unroll
  for (int mt = 0; mt < 2; ++mt)
#pragma unroll
    for (int j = 0; j < NTW; ++j) acc[mt][j] = (f32x4){0.f, 0.f, 0.f, 0.f};

  const short8* Bw = (const short8*)WhF + lane;

  // ---- stage helpers: linear chunk index over the 48KB fp32 half-panel.
  // load pair q of round J0: d0 = 2*((J0+q)*128 + tid) -> (row, 16B-chunk cr)
  // write: m = (J0+q)*128 + tid -> bf16 16B-chunk (row, crb), crb ^= row&7
#define STG_LOAD(R, J0, h)                                                   \
  { _Pragma("unroll") for (int q = 0; q < 4; ++q) {                          \
      int d0 = 2 * (((J0) + q) * 128 + tid);                                 \
      int rw = d0 / 96, cr = d0 - rw * 96;                                   \
      const float* gp = Hblk + (size_t)rw * HIDn + (h) * 384 + cr * 4;       \
      R[q][0] = *(const float4*)gp;                                          \
      R[q][1] = *(const float4*)(gp + 4);                                    \
  } }
#define STG_WRITE(R, J0)                                                     \
  { _Pragma("unroll") for (int q = 0; q < 4; ++q) {                          \
      int m = ((J0) + q) * 128 + tid;                                        \
      int rw = m / 48, crb = m - rw * 48;                                    \
      short8 t;                                                              \
      t[0] = f2bf(R[q][0].x); t[1] = f2bf(R[q][0].y);                        \
      t[2] = f2bf(R[q][0].z); t[3] = f2bf(R[q][0].w);                        \
      t[4] = f2bf(R[q][1].x); t[5] = f2bf(R[q][1].y);                        \
      t[6] = f2bf(R[q][1].z); t[7] = f2bf(R[q][1].w);                        \
      *(short8*)&Abf[rw * 384 + ((crb ^ (rw & 7)) << 3)] = t;                \
  } }

#pragma unroll
  for (int h = 0; h < 2; ++h) {
    // ---- stage K-half h: 48KB fp32 -> 24KB bf16 LDS (3 overlapped rounds)
    {
      float4 rA[4][2], rB[4][2], rC[4][2];
      STG_LOAD(rA, 0, h);
      STG_LOAD(rB, 4, h);
      STG_WRITE(rA, 0);
      STG_LOAD(rC, 8, h);
      STG_WRITE(rB, 4);
      STG_WRITE(rC, 8);
    }
    __syncthreads();             // half-panel visible to both waves

    // ---- 12 K-steps on this half
#pragma unroll
    for (int ks = 0; ks < 12; ++ks) {
      int kk = h * 12 + ks;
      short8 bfr[NTW];
#pragma unroll
      for (int j = 0; j < NTW; ++j)
        bfr[j] = Bw[(kk * NT + nh * NTW + j) * 64];
      int ca = (((ks << 2) | quad) ^ (l16 & 7)) << 3;   // swizzled chunk (bf16 idx)
      short8 a0 = *(const short8*)&Abf[l16 * 384 + ca];
      short8 a1 = *(const short8*)&Abf[(l16 + 16) * 384 + ca];
#pragma unroll
      for (int j = 0; j < NTW; ++j) {
        acc[0][j] = __builtin_amdgcn_mfma_f32_16x16x32_bf16(a0, bfr[j], acc[0][j], 0, 0, 0);
        acc[1][j] = __builtin_amdgcn_mfma_f32_16x16x32_bf16(a1, bfr[j], acc[1][j], 0, 0, 0);
      }
    }
    if (h == 0) __syncthreads(); // all reads of half 0 done before restage
  }

  // ---- partial scores over this wave's 112 n-cols, reduced over l16
  {
    const float* bp = biasP + (size_t)b * NPAD + nh * (NTW * 16) + l16;
    const float* vp = vP + nh * (NTW * 16) + l16;
    float bv[NTW], vv[NTW];
#pragma unroll
    for (int j = 0; j < NTW; ++j) { bv[j] = bp[j * 16]; vv[j] = vp[j * 16]; }
#pragma unroll
    for (int mt = 0; mt < 2; ++mt)
#pragma unroll
      for (int r = 0; r < 4; ++r) {
        float s = 0.f;
#pragma unroll
        for (int j = 0; j < NTW; ++j)
          s += fast_tanh(acc[mt][j][r] + bv[j]) * vv[j];
        s += __shfl_xor(s, 1); s += __shfl_xor(s, 2);
        s += __shfl_xor(s, 4); s += __shfl_xor(s, 8);
        if (l16 == 0) scp[nh][mt * 16 + quad * 4 + r] = s;
      }
  }
  __syncthreads();

  // ---- segment softmax (redundant per wave; lane j <-> row j, lanes>=32 -inf)
  int beg = offs[b * (MSEG + 1) + seg];
  int nxt = offs[b * (MSEG + 1) + seg + 1];
  bool valid = (beg != -1);
  int end = (nxt == -1) ? Sn : nxt - 1;

  float x = -INFINITY;
  if (lane < 32) {
    int rw = s0 + lane;
    if (valid && rw >= beg && rw < end)
      x = scp[0][lane] + scp[1][lane];
  }
  float mx = x;
  mx = fmaxf(mx, __shfl_xor(mx, 1));  mx = fmaxf(mx, __shfl_xor(mx, 2));
  mx = fmaxf(mx, __shfl_xor(mx, 4));  mx = fmaxf(mx, __shfl_xor(mx, 8));
  mx = fmaxf(mx, __shfl_xor(mx, 16)); mx = fmaxf(mx, __shfl_xor(mx, 32));
  float mm = (mx > -1e30f) ? mx : 0.f;
  float e = __expf(x - mm);            // exp(-inf)=0 handles masking
  float ls = e;
  ls += __shfl_xor(ls, 1);  ls += __shfl_xor(ls, 2);
  ls += __shfl_xor(ls, 4);  ls += __shfl_xor(ls, 8);
  ls += __shfl_xor(ls, 16); ls += __shfl_xor(ls, 32);
  float inv = (ls > 0.f) ? 1.f / ls : 0.f;
  float av = e * inv;                  // alpha of row `lane` (lane<32)

  // alphas for this wave's 16 rows, into registers
  float af[16];
#pragma unroll
  for (int i = 0; i < 16; ++i) af[i] = __shfl(av, wave * 16 + i);

  // ---- weighted sum: wave handles rows s0+wave*16 .. +16, full 768 cols,
  // branchless (masked rows have alpha exactly 0); H rows are L2/L3-hot
  const float4* Hrow = (const float4*)(H + (size_t)(b * Sn + s0 + wave * 16) * HIDn);
  float4 o0 = {0,0,0,0}, o1 = {0,0,0,0}, o2 = {0,0,0,0};
#pragma unroll 4
  for (int i = 0; i < 16; ++i) {
    const float4* hp = Hrow + (size_t)i * (HIDn / 4);
    float4 h0 = hp[lane], h1 = hp[lane + 64], h2 = hp[lane + 128];
    float a = af[i];
    o0.x += a * h0.x; o0.y += a * h0.y; o0.z += a * h0.z; o0.w += a * h0.w;
    o1.x += a * h1.x; o1.y += a * h1.y; o1.z += a * h1.z; o1.w += a * h1.w;
    o2.x += a * h2.x; o2.y += a * h2.y; o2.z += a * h2.z; o2.w += a * h2.w;
  }
  {
    float4* ol = (float4*)o_l[wave];
    ol[lane] = o0; ol[lane + 64] = o1; ol[lane + 128] = o2;
  }
  __syncthreads();

  // ---- combine the 2 wave partials + store (192 float4 by 128 threads)
  {
    const float4* p0 = (const float4*)o_l[0];
    const float4* p1 = (const float4*)o_l[1];
    float4* op = (float4*)(out + ((size_t)b * MSEG + seg) * HIDn);
#pragma unroll
    for (int base = 0; base < 192; base += 128) {
      int idx = base + tid;
      if (idx < 192) {
        float4 a0 = p0[idx], a1 = p1[idx];
        float4 s;
        s.x = a0.x + a1.x; s.y = a0.y + a1.y;
        s.z = a0.z + a1.z; s.w = a0.w + a1.w;
        op[idx] = s;
      }
    }
  }
}

extern "C" void kernel_launch(void* const* d_in, const int* in_sizes, int n_in,
                              void* d_out, int out_size, void* d_ws, size_t ws_size,
                              hipStream_t stream) {
  const float* H    = (const float*)d_in[0];
  const float* u    = (const float*)d_in[1];
  const float* p    = (const float*)d_in[2];
  const float* Wh   = (const float*)d_in[3];
  const float* Wu   = (const float*)d_in[4];
  const float* Wp   = (const float*)d_in[5];
  const float* v    = (const float*)d_in[6];
  const float* bvec = (const float*)d_in[7];
  const int*   offs = (const int*)d_in[8];
  float* out = (float*)d_out;

  // ws layout: biasP[128*224] | vP[224] | WhF (bf16 224*768, fragment order)
  float* biasP = (float*)d_ws;
  float* vP    = biasP + (size_t)Bn * NPAD;
  unsigned short* WhF = (unsigned short*)(vP + NPAD);

  setup_kernel<<<(NPAD * HIDn + 255) / 256, 256, 0, stream>>>(Wh, v, WhF, vP);
  bias_kernel<<<Bn, 256, 0, stream>>>(u, p, Wu, Wp, bvec, biasP);
  fused_kernel<<<(Bn * Sn) / ROWS, 128, 0, stream>>>(H, WhF, biasP, vP, offs, out);
}

// Round 5
// 347.440 us; speedup vs baseline: 1.1272x; 1.1272x over previous
//
#include <hip/hip_runtime.h>
#include <math.h>

#define Bn   128
#define Sn   512
#define HIDn 768
#define OUTn 200
#define MSEG 16
#define NPAD 256   // OUT padded to 16 MFMA n-tiles of 16
#define NT   16
#define NTW  4     // n-tiles per wave (4-way N split, no intra-block B redundancy)
#define NQ   4     // K staging quarters
#define KQ   6     // k-steps (of 32) per quarter
#define ROWS 32    // rows per block (1 segment); block = 256 thr = 4 waves
#define NREP 8     // WhF replication factor (L2 same-address spread)

typedef __attribute__((ext_vector_type(8))) short short8;
typedef __attribute__((ext_vector_type(4))) float f32x4;

// fp32 -> bf16 round-to-nearest-even (finite inputs)
static __device__ inline unsigned short f2bf(float f) {
  union { float f; unsigned u; } v; v.f = f;
  unsigned r = v.u + 0x7FFFu + ((v.u >> 16) & 1u);
  return (unsigned short)(r >> 16);
}

// saturating fast tanh: e = exp(-2|x|) in (0,1], never overflows
static __device__ inline float fast_tanh(float x) {
  float t = fabsf(x);
  float e = __expf(-2.f * t);
  float r = (1.f - e) * __builtin_amdgcn_rcpf(1.f + e);
  return copysignf(r, x);
}

// one-time: WhF = bf16(Wh^T) in MFMA B-fragment order, replicated nrep times:
// elem (n,k) -> ((k>>5)*NT + (n>>4))*512 + ((k>>3)&3)*128 + (n&15)*8 + (k&7)
// Cols 200..255 zero-padded.  vP = v zero-padded to NPAD.
__global__ __launch_bounds__(256) void setup_kernel(
    const float* __restrict__ Wh, const float* __restrict__ v,
    unsigned short* __restrict__ WhF, float* __restrict__ vP, int nrep) {
  int idx = blockIdx.x * 256 + threadIdx.x;   // grid 768 -> 196608 = NPAD*HIDn
  if (blockIdx.x == 0 && threadIdx.x < NPAD)
    vP[threadIdx.x] = (threadIdx.x < OUTn) ? v[threadIdx.x] : 0.f;
  if (idx < NPAD * HIDn) {
    int n = idx / HIDn;
    int k = idx - n * HIDn;
    float val = (n < OUTn) ? Wh[(size_t)k * OUTn + n] : 0.f;
    size_t d = ((size_t)(k >> 5) * NT + (n >> 4)) * 512
             + ((k >> 3) & 3) * 128 + (n & 15) * 8 + (k & 7);
    unsigned short bv = f2bf(val);
    for (int r = 0; r < nrep; ++r)
      WhF[(size_t)r * ((size_t)NPAD * HIDn) + d] = bv;
  }
}

// biasP[b][n] = b[n] + u[b]@Wu[:,n] + p[b]@Wp[:,n], zero-padded to NPAD
__global__ __launch_bounds__(256) void bias_kernel(
    const float* __restrict__ u, const float* __restrict__ p,
    const float* __restrict__ Wu, const float* __restrict__ Wp,
    const float* __restrict__ bvec, float* __restrict__ biasP) {
  int b = blockIdx.x;
  __shared__ float ul[OUTn], pl[OUTn];
  int tid = threadIdx.x;
  if (tid < OUTn) { ul[tid] = u[b * OUTn + tid]; pl[tid] = p[b * OUTn + tid]; }
  __syncthreads();
  float s0 = 0.f, s1 = 0.f;
  if (tid < OUTn) {
    s0 = bvec[tid];
    for (int k = 0; k < OUTn; k += 2) {
      s0 += ul[k] * Wu[k * OUTn + tid] + pl[k] * Wp[k * OUTn + tid];
      s1 += ul[k + 1] * Wu[(k + 1) * OUTn + tid] + pl[k + 1] * Wp[(k + 1) * OUTn + tid];
    }
  }
  biasP[(size_t)b * NPAD + tid] = s0 + s1;
}

// Fused: block = 256 thr = 4 waves = 32 rows (1 segment).  MAX OCCUPANCY
// design: 12.8KB LDS (single A-quarter buffer; epilogue partials alias it)
// -> 8 blocks/CU = 32 waves/CU (4x every prior round).  Wave w owns n-tiles
// 4w..4w+3 over ALL 32 rows (acc 2x4; no intra-block B duplication).  Next
// K-quarter prefetched into 6 regs DURING compute (T14); A converted to bf16
// at stage time; chunk-XOR swizzle -> 2-way (free) ds_read_b128.  WhF read
// from replica bid&repmask to spread same-address L2 traffic.
__global__ __launch_bounds__(256) void fused_kernel(
    const float* __restrict__ H, const unsigned short* __restrict__ WhF,
    const float* __restrict__ biasP, const float* __restrict__ vP,
    const int* __restrict__ offs, float* __restrict__ out, int repmask) {
  __shared__ unsigned char __attribute__((aligned(16))) smraw[ROWS * 192 * 2]; // 12288B
  __shared__ float scp[4][ROWS];       // per-wave partial scores
  unsigned short* sma = (unsigned short*)smraw;           // staged A quarter
  float (*smo)[HIDn] = (float (*)[HIDn])smraw;            // epilogue partials

  int tid = threadIdx.x, wave = tid >> 6, lane = tid & 63;
  int quad = lane >> 4, l16 = lane & 15;
  int bid = blockIdx.x;
  int b = bid >> 4;              // 16 blocks (segments) per batch
  int seg = bid & 15;
  int s0 = seg << 5;

  const float* Hblk = H + (size_t)(b * Sn + s0) * HIDn;

  // ---- staging addressing: bf16 16B-chunk m = w*256+tid -> row r=m/24,
  // chunk c=m%24 (k-range c*8..+8 within quarter); LDS slot c^(r&7)
  const float* gp_[3]; int ldst_[3];
#pragma unroll
  for (int w = 0; w < 3; ++w) {
    int m = w * 256 + tid;
    int r = m / 24, c = m - r * 24;
    gp_[w] = Hblk + (size_t)r * HIDn + c * 8;
    ldst_[w] = r * 192 + ((c ^ (r & 7)) << 3);
  }

  f32x4 acc[2][NTW];
#pragma unroll
  for (int mt = 0; mt < 2; ++mt)
#pragma unroll
    for (int j = 0; j < NTW; ++j) acc[mt][j] = (f32x4){0.f, 0.f, 0.f, 0.f};

  const short8* Bw = (const short8*)(WhF +
      (size_t)(bid & repmask) * ((size_t)NPAD * HIDn)) + lane;

  // prologue: prefetch quarter 0 into regs
  float4 R[3][2];
#pragma unroll
  for (int w = 0; w < 3; ++w) {
    R[w][0] = *(const float4*)gp_[w];
    R[w][1] = *(const float4*)(gp_[w] + 4);
  }

#pragma unroll
  for (int p = 0; p < NQ; ++p) {
    // write prefetched quarter to LDS (convert to bf16, swizzled)
#pragma unroll
    for (int w = 0; w < 3; ++w) {
      short8 t;
      t[0] = f2bf(R[w][0].x); t[1] = f2bf(R[w][0].y);
      t[2] = f2bf(R[w][0].z); t[3] = f2bf(R[w][0].w);
      t[4] = f2bf(R[w][1].x); t[5] = f2bf(R[w][1].y);
      t[6] = f2bf(R[w][1].z); t[7] = f2bf(R[w][1].w);
      *(short8*)&sma[ldst_[w]] = t;
    }
    __syncthreads();
    // issue next quarter's loads; they fly under this quarter's compute
    if (p + 1 < NQ) {
#pragma unroll
      for (int w = 0; w < 3; ++w) {
        R[w][0] = *(const float4*)(gp_[w] + (p + 1) * 192);
        R[w][1] = *(const float4*)(gp_[w] + (p + 1) * 192 + 4);
      }
    }
#pragma unroll
    for (int ks = 0; ks < KQ; ++ks) {
      int kk = p * KQ + ks;
      short8 bfr[NTW];
#pragma unroll
      for (int j = 0; j < NTW; ++j)
        bfr[j] = Bw[(kk * NT + wave * NTW + j) * 64];
      int cs = (((ks << 2) | quad) ^ (l16 & 7)) << 3;   // swizzled chunk (ushort idx)
      short8 a0 = *(const short8*)&sma[l16 * 192 + cs];
      short8 a1 = *(const short8*)&sma[(l16 + 16) * 192 + cs];
#pragma unroll
      for (int j = 0; j < NTW; ++j) {
        acc[0][j] = __builtin_amdgcn_mfma_f32_16x16x32_bf16(a0, bfr[j], acc[0][j], 0, 0, 0);
        acc[1][j] = __builtin_amdgcn_mfma_f32_16x16x32_bf16(a1, bfr[j], acc[1][j], 0, 0, 0);
      }
    }
    __syncthreads();             // all reads of this quarter done -> buffer free
  }

  // ---- partial scores over this wave's 64 n-cols, reduced over l16
  {
    const float* bp = biasP + (size_t)b * NPAD + wave * 64 + l16;
    const float* vp = vP + wave * 64 + l16;
    float bv[NTW], vv[NTW];
#pragma unroll
    for (int j = 0; j < NTW; ++j) { bv[j] = bp[j * 16]; vv[j] = vp[j * 16]; }
#pragma unroll
    for (int mt = 0; mt < 2; ++mt)
#pragma unroll
      for (int r = 0; r < 4; ++r) {
        float s = 0.f;
#pragma unroll
        for (int j = 0; j < NTW; ++j)
          s += fast_tanh(acc[mt][j][r] + bv[j]) * vv[j];
        s += __shfl_xor(s, 1); s += __shfl_xor(s, 2);
        s += __shfl_xor(s, 4); s += __shfl_xor(s, 8);
        if (l16 == 0) scp[wave][mt * 16 + quad * 4 + r] = s;
      }
  }
  __syncthreads();

  // ---- segment softmax (redundant per wave; lane j <-> row j, lanes>=32 -inf)
  int beg = offs[b * (MSEG + 1) + seg];
  int nxt = offs[b * (MSEG + 1) + seg + 1];
  bool valid = (beg != -1);
  int end = (nxt == -1) ? Sn : nxt - 1;

  float x = -INFINITY;
  if (lane < 32) {
    int rw = s0 + lane;
    if (valid && rw >= beg && rw < end)
      x = scp[0][lane] + scp[1][lane] + scp[2][lane] + scp[3][lane];
  }
  float mx = x;
  mx = fmaxf(mx, __shfl_xor(mx, 1));  mx = fmaxf(mx, __shfl_xor(mx, 2));
  mx = fmaxf(mx, __shfl_xor(mx, 4));  mx = fmaxf(mx, __shfl_xor(mx, 8));
  mx = fmaxf(mx, __shfl_xor(mx, 16)); mx = fmaxf(mx, __shfl_xor(mx, 32));
  float mm = (mx > -1e30f) ? mx : 0.f;
  float e = __expf(x - mm);            // exp(-inf)=0 handles masking
  float ls = e;
  ls += __shfl_xor(ls, 1);  ls += __shfl_xor(ls, 2);
  ls += __shfl_xor(ls, 4);  ls += __shfl_xor(ls, 8);
  ls += __shfl_xor(ls, 16); ls += __shfl_xor(ls, 32);
  float inv = (ls > 0.f) ? 1.f / ls : 0.f;
  float av = e * inv;                  // alpha of row `lane` (lane<32)

  // alphas for this wave's 8 rows, into registers
  float af[8];
#pragma unroll
  for (int i = 0; i < 8; ++i) af[i] = __shfl(av, wave * 8 + i);

  // ---- weighted sum: wave handles rows s0+wave*8 .. +8, full 768 cols,
  // branchless (masked rows have alpha exactly 0); H rows are L2-hot
  const float4* Hrow = (const float4*)(H + (size_t)(b * Sn + s0 + wave * 8) * HIDn);
  float4 o0 = {0,0,0,0}, o1 = {0,0,0,0}, o2 = {0,0,0,0};
#pragma unroll
  for (int i = 0; i < 8; ++i) {
    const float4* hp = Hrow + (size_t)i * (HIDn / 4);
    float4 h0 = hp[lane], h1 = hp[lane + 64], h2 = hp[lane + 128];
    float a = af[i];
    o0.x += a * h0.x; o0.y += a * h0.y; o0.z += a * h0.z; o0.w += a * h0.w;
    o1.x += a * h1.x; o1.y += a * h1.y; o1.z += a * h1.z; o1.w += a * h1.w;
    o2.x += a * h2.x; o2.y += a * h2.y; o2.z += a * h2.z; o2.w += a * h2.w;
  }
  {
    float4* ol = (float4*)smo[wave];   // aliases sma: last read was pre-barrier
    ol[lane] = o0; ol[lane + 64] = o1; ol[lane + 128] = o2;
  }
  __syncthreads();

  // ---- combine 4 partials + store (192 threads x float4 = 768 cols)
  if (tid < 192) {
    const float4* p0 = (const float4*)smo[0];
    const float4* p1 = (const float4*)smo[1];
    const float4* p2 = (const float4*)smo[2];
    const float4* p3 = (const float4*)smo[3];
    float4 a0 = p0[tid], a1 = p1[tid], a2 = p2[tid], a3 = p3[tid];
    float4 s;
    s.x = a0.x + a1.x + a2.x + a3.x;
    s.y = a0.y + a1.y + a2.y + a3.y;
    s.z = a0.z + a1.z + a2.z + a3.z;
    s.w = a0.w + a1.w + a2.w + a3.w;
    ((float4*)(out + ((size_t)b * MSEG + seg) * HIDn))[tid] = s;
  }
}

extern "C" void kernel_launch(void* const* d_in, const int* in_sizes, int n_in,
                              void* d_out, int out_size, void* d_ws, size_t ws_size,
                              hipStream_t stream) {
  const float* H    = (const float*)d_in[0];
  const float* u    = (const float*)d_in[1];
  const float* p    = (const float*)d_in[2];
  const float* Wh   = (const float*)d_in[3];
  const float* Wu   = (const float*)d_in[4];
  const float* Wp   = (const float*)d_in[5];
  const float* v    = (const float*)d_in[6];
  const float* bvec = (const float*)d_in[7];
  const int*   offs = (const int*)d_in[8];
  float* out = (float*)d_out;

  // ws layout: biasP[128*256] | vP[256] | WhF (bf16 256*768, fragment order,
  // replicated NREP times if workspace allows)
  float* biasP = (float*)d_ws;
  float* vP    = biasP + (size_t)Bn * NPAD;
  unsigned short* WhF = (unsigned short*)(vP + NPAD);
  size_t fixed = (size_t)Bn * NPAD * 4 + (size_t)NPAD * 4;
  size_t whfB  = (size_t)NPAD * HIDn * 2;
  int nrep = (ws_size >= fixed + (size_t)NREP * whfB) ? NREP : 1;
  int repmask = nrep - 1;

  setup_kernel<<<(NPAD * HIDn + 255) / 256, 256, 0, stream>>>(Wh, v, WhF, vP, nrep);
  bias_kernel<<<Bn, 256, 0, stream>>>(u, p, Wu, Wp, bvec, biasP);
  fused_kernel<<<(Bn * Sn) / ROWS, 256, 0, stream>>>(H, WhF, biasP, vP, offs, out, repmask);
}